// Round 4
// baseline (500.395 us; speedup 1.0000x reference)
//
#include <hip/hip_runtime.h>

// SAR quantizer: q, Q, Wn outputs.
// L=524288 rows, A=24 ADCs, B=8 bits, M=36 coefficient rows.
// VR = VREF = 1.8 / 2^3 = 0.225, noise scale = 0.01**0.5 = 0.1.
//
// *** R4 = DIAGNOSTIC PROBE — intentionally slowed with s_sleep. ***
// The harness's 260us fill dispatches crowd our 132us kernel out of
// rocprof_to_text --top-k 5, so we have never seen OUR counters. Adding
// ~220us of pure s_sleep (no counter pollution; outputs bit-identical)
// pushes our dispatch into the top-5. Readouts wanted:
//   - FETCH_SIZE: ~49,000 KB => no RMW on Q stores; ~400,000+ KB => RMW real.
//   - OH = bench dur_us - our dispatch dur_us => fixed replay overhead.
//   - VGPR_Count (spill check), OccupancyPercent.
// REMOVE THE SLEEPS NEXT ROUND.

#define L_TOT   524288
#define A_ADC   24
#define M_ROWS  36
#define B_BITS  8
#define BLK     384
#define NBLK    1024
#define NXCD    8

// XOR bank-quad swizzle (involution, bijective on [0,128)).
__device__ __forceinline__ int swz(int c) { return c ^ ((c >> 3) & 7); }

__global__ __launch_bounds__(BLK) void sar_kernel(
    const float* __restrict__ x,
    const float* __restrict__ W,
    const float* __restrict__ nz,
    float* __restrict__ out_q,
    float* __restrict__ out_Q,
    float* __restrict__ out_Wn,
    long long N)
{
    // Bijective XCD swizzle (kept from R3; neutral but harmless).
    const int bid = blockIdx.x;
    const int sb  = (bid & (NXCD - 1)) * (NBLK / NXCD) + (bid >> 3);

    const long long gid = (long long)sb * BLK + threadIdx.x;
    const long long T   = (long long)NBLK * BLK;   // 393216, multiple of 24
    const int a = threadIdx.x % 24;  // fixed ADC column (BLK % 24 == 0)
    const int w = threadIdx.x >> 6;  // wave id in block (0..5)
    const int l = threadIdx.x & 63;  // lane

    __shared__ float4 stage[BLK / 64][128]; // 2KB per wave, wave-private

    // Per-a coefficients: c[r] = (W[r][a] + noise[r][a]*0.1f) * 0.225f
    float c[M_ROWS];
#pragma unroll
    for (int r = 0; r < M_ROWS; ++r) {
        float wn = W[r * A_ADC + a] + nz[r * A_ADC + a] * 0.1f;
        c[r] = wn * 0.225f;
    }

    // Wn tail output (864 floats), once, deterministic.
    if (gid < (long long)(M_ROWS * A_ADC)) {
        out_Wn[gid] = W[gid] + nz[gid] * 0.1f;
    }

    // Software pipeline: xv holds x[i] entering each iteration.
    float xv = (gid < N) ? x[gid] : 0.0f;

    for (long long i = gid; i < N; i += T) {
        const long long inext = i + T;
        float xnext = 0.0f;
        if (inext < N) xnext = x[inext];

        float q[B_BITS];

        // Bit-serial SAR, fully unrolled; m indices are compile-time.
        int m = M_ROWS - 1;
#pragma unroll
        for (int jj = 0; jj < B_BITS; ++jj) {
            const int j = B_BITS - 1 - jj;
            float bs = c[m]; --m;          // Wn[m]*VREF
#pragma unroll
            for (int k = j + 1; k < B_BITS; ++k) {
                float t = (q[k] + 1.0f) * 0.5f;
                bs += t * c[m];
                --m;
            }
            float s = (xv - bs) + 1e-30f;
            q[j] = (s > 0.0f) ? 1.0f : ((s < 0.0f) ? -1.0f : 0.0f);
        }

        // q = sum_j (q_j+1)/2 * (0.225 * 2^j), ascending j
        float acc = 0.0f;
#pragma unroll
        for (int j = 0; j < B_BITS; ++j) {
            float t = (q[j] + 1.0f) * 0.5f;
            float bwj = 0.225f * (float)(1 << j);
            acc += t * bwj;
        }
        out_q[i] = acc;

        // Q output via LDS staging (dense 1KB per store instruction).
        const int c0 = 2 * l, c1 = 2 * l + 1;
        stage[w][swz(c0)] = make_float4(q[0], q[1], q[2], q[3]);
        stage[w][swz(c1)] = make_float4(q[4], q[5], q[6], q[7]);
        const long long base_w = i - l;
        float4* Qw = (float4*)(out_Q + base_w * 8);
        const int r0 = l, r1 = 64 + l;
        Qw[r0] = stage[w][swz(r0)];
        Qw[r1] = stage[w][swz(r1)];

        xv = xnext;

        // DIAGNOSTIC ONLY: ~16K idle clocks/iter (~220us total) to push this
        // dispatch into rocprof top-5. No memory/VALU counter pollution.
        __builtin_amdgcn_s_sleep(127);
        __builtin_amdgcn_s_sleep(127);
    }
}

extern "C" void kernel_launch(void* const* d_in, const int* in_sizes, int n_in,
                              void* d_out, int out_size, void* d_ws, size_t ws_size,
                              hipStream_t stream) {
    const float* x  = (const float*)d_in[0];
    const float* W  = (const float*)d_in[1];
    const float* nz = (const float*)d_in[2];
    float* out = (float*)d_out;

    const long long N = (long long)L_TOT * A_ADC;   // 12,582,912
    float* out_q  = out;
    float* out_Q  = out + N;
    float* out_Wn = out + N + N * (long long)B_BITS;

    sar_kernel<<<NBLK, BLK, 0, stream>>>(x, W, nz, out_q, out_Q, out_Wn, N);
}

// Round 6
// 99.147 us; speedup vs baseline: 5.0470x; 5.0470x over previous
//
#include <hip/hip_runtime.h>

// SAR quantizer: q, Q, Wn outputs.
// L=524288 rows, A=24 ADCs, B=8 bits, M=36 coefficient rows.
// VR = VREF = 1.8 / 2^3 = 0.225, noise scale = 0.01**0.5 = 0.1.
//
// R5 changes (arithmetic untouched — still bit-exact):
//  - NBLK 1024 -> 2048: 8 blocks/CU -> full 32-wave/CU residency (was 24).
//    R4 counters showed compute (~40us VALU) and memory (~72us floor) are
//    not overlapping (132us ~= sum); more independent waves per CU overlap
//    one wave's serial SAR chain with other waves' store bursts.
//  - Nontemporal stores for q/Q/Wn: outputs are write-once, never re-read;
//    nt bypasses L2/L3 allocation (no dirty-line churn, faster store ack,
//    stops evicting x from L3).
//  - R5b: use clang ext_vector float4 (f32x4) for the nt stores —
//    __builtin_nontemporal_store rejects HIP's float4 class type.

#define L_TOT   524288
#define A_ADC   24
#define M_ROWS  36
#define B_BITS  8
#define BLK     384
#define NBLK    2048
#define NXCD    8

typedef float f32x4 __attribute__((ext_vector_type(4)));

// XOR bank-quad swizzle (involution, bijective on [0,128)).
__device__ __forceinline__ int swz(int c) { return c ^ ((c >> 3) & 7); }

__global__ __launch_bounds__(BLK) void sar_kernel(
    const float* __restrict__ x,
    const float* __restrict__ W,
    const float* __restrict__ nz,
    float* __restrict__ out_q,
    float* __restrict__ out_Q,
    float* __restrict__ out_Wn,
    long long N)
{
    // Bijective XCD swizzle (NBLK % 8 == 0).
    const int bid = blockIdx.x;
    const int sb  = (bid & (NXCD - 1)) * (NBLK / NXCD) + (bid >> 3);

    const long long gid = (long long)sb * BLK + threadIdx.x;
    const long long T   = (long long)NBLK * BLK;   // 786432 = 24 * 32768
    const int a = threadIdx.x % 24;  // fixed ADC column (BLK % 24 == 0)
    const int w = threadIdx.x >> 6;  // wave id in block (0..5)
    const int l = threadIdx.x & 63;  // lane

    __shared__ f32x4 stage[BLK / 64][128]; // 2KB per wave, wave-private

    // Per-a coefficients: c[r] = (W[r][a] + noise[r][a]*0.1f) * 0.225f
    float c[M_ROWS];
#pragma unroll
    for (int r = 0; r < M_ROWS; ++r) {
        float wn = W[r * A_ADC + a] + nz[r * A_ADC + a] * 0.1f;
        c[r] = wn * 0.225f;
    }

    // Wn tail output (864 floats), once (gid is a bijection of thread id).
    if (gid < (long long)(M_ROWS * A_ADC)) {
        __builtin_nontemporal_store(W[gid] + nz[gid] * 0.1f, &out_Wn[gid]);
    }

    // Software pipeline: xv holds x[i] entering each iteration.
    float xv = (gid < N) ? x[gid] : 0.0f;

    for (long long i = gid; i < N; i += T) {
        // Prefetch next iteration's x before this iteration's stores.
        const long long inext = i + T;
        float xnext = 0.0f;
        if (inext < N) xnext = x[inext];

        float q[B_BITS];

        // Bit-serial SAR, fully unrolled; m indices are compile-time.
        int m = M_ROWS - 1;
#pragma unroll
        for (int jj = 0; jj < B_BITS; ++jj) {
            const int j = B_BITS - 1 - jj;
            float bs = c[m]; --m;          // Wn[m]*VREF
#pragma unroll
            for (int k = j + 1; k < B_BITS; ++k) {
                // (q_k + 1)*0.5 in {0, 0.5, 1} -> product exact; add in
                // the same k-ascending order as the reference.
                float t = (q[k] + 1.0f) * 0.5f;
                bs += t * c[m];
                --m;
            }
            float s = (xv - bs) + 1e-30f;
            q[j] = (s > 0.0f) ? 1.0f : ((s < 0.0f) ? -1.0f : 0.0f);
        }

        // q = sum_j (q_j+1)/2 * (0.225 * 2^j), ascending j
        float acc = 0.0f;
#pragma unroll
        for (int j = 0; j < B_BITS; ++j) {
            float t = (q[j] + 1.0f) * 0.5f;
            float bwj = 0.225f * (float)(1 << j);  // exact pow2 scaling
            acc += t * bwj;
        }
        __builtin_nontemporal_store(acc, &out_q[i]);

        // --- Q output via LDS staging ---
        // Wave's 64 consecutive elements form a dense 2KB region of Q.
        // Stage 8 floats/lane, flush as two contiguous-1KB instructions.
        f32x4 v0; v0.x = q[0]; v0.y = q[1]; v0.z = q[2]; v0.w = q[3];
        f32x4 v1; v1.x = q[4]; v1.y = q[5]; v1.z = q[6]; v1.w = q[7];
        const int c0 = 2 * l, c1 = 2 * l + 1;
        stage[w][swz(c0)] = v0;
        stage[w][swz(c1)] = v1;
        // wave-private region: no barrier needed; compiler inserts lgkmcnt.
        const long long base_w = i - l;              // wave's first element
        f32x4* Qw = (f32x4*)(out_Q + base_w * 8);    // float4 index space
        const int r0 = l, r1 = 64 + l;
        __builtin_nontemporal_store(stage[w][swz(r0)], &Qw[r0]);
        __builtin_nontemporal_store(stage[w][swz(r1)], &Qw[r1]);

        xv = xnext;
    }
}

extern "C" void kernel_launch(void* const* d_in, const int* in_sizes, int n_in,
                              void* d_out, int out_size, void* d_ws, size_t ws_size,
                              hipStream_t stream) {
    const float* x  = (const float*)d_in[0];
    const float* W  = (const float*)d_in[1];
    const float* nz = (const float*)d_in[2];
    float* out = (float*)d_out;

    const long long N = (long long)L_TOT * A_ADC;   // 12,582,912
    float* out_q  = out;
    float* out_Q  = out + N;
    float* out_Wn = out + N + N * (long long)B_BITS;

    // 2048 blocks x 384 threads: stride = 786432 (multiple of 24),
    // exactly 16 grid-stride iterations; 8 blocks/CU -> 32 waves/CU.
    sar_kernel<<<NBLK, BLK, 0, stream>>>(x, W, nz, out_q, out_Q, out_Wn, N);
}

// Round 7
// 95.930 us; speedup vs baseline: 5.2163x; 1.0335x over previous
//
#include <hip/hip_runtime.h>

// SAR quantizer: q, Q, Wn outputs.
// L=524288 rows, A=24 ADCs, B=8 bits, M=36 coefficient rows.
// VR = VREF = 1.8 / 2^3 = 0.225, noise scale = 0.01**0.5 = 0.1.
//
// R7 change (single variable; arithmetic untouched — still bit-exact):
//  - Prefetch distance 1 -> 2. vmcnt retires IN ORDER: with distance-1 the
//    load a wave waits on each iteration sits behind the previous
//    iteration's nt stores in the VMEM FIFO, so every iteration's compute
//    was gated on prior store ACKs (~HBM latency) -> wave-iter latency
//    ~9900 cyc, perf scaled linearly with waves (132us@24w -> 99us@32w).
//    With distance-2 the awaited load is always OLDER than any store in
//    the queue, so store ACK latency leaves the critical path.

#define L_TOT   524288
#define A_ADC   24
#define M_ROWS  36
#define B_BITS  8
#define BLK     384
#define NBLK    2048
#define NXCD    8

typedef float f32x4 __attribute__((ext_vector_type(4)));

// XOR bank-quad swizzle (involution, bijective on [0,128)).
__device__ __forceinline__ int swz(int c) { return c ^ ((c >> 3) & 7); }

__global__ __launch_bounds__(BLK) void sar_kernel(
    const float* __restrict__ x,
    const float* __restrict__ W,
    const float* __restrict__ nz,
    float* __restrict__ out_q,
    float* __restrict__ out_Q,
    float* __restrict__ out_Wn,
    long long N)
{
    // Bijective XCD swizzle (NBLK % 8 == 0).
    const int bid = blockIdx.x;
    const int sb  = (bid & (NXCD - 1)) * (NBLK / NXCD) + (bid >> 3);

    const long long gid = (long long)sb * BLK + threadIdx.x;
    const long long T   = (long long)NBLK * BLK;   // 786432 = 24 * 32768
    const int a = threadIdx.x % 24;  // fixed ADC column (BLK % 24 == 0)
    const int w = threadIdx.x >> 6;  // wave id in block (0..5)
    const int l = threadIdx.x & 63;  // lane

    __shared__ f32x4 stage[BLK / 64][128]; // 2KB per wave, wave-private

    // Per-a coefficients: c[r] = (W[r][a] + noise[r][a]*0.1f) * 0.225f
    float c[M_ROWS];
#pragma unroll
    for (int r = 0; r < M_ROWS; ++r) {
        float wn = W[r * A_ADC + a] + nz[r * A_ADC + a] * 0.1f;
        c[r] = wn * 0.225f;
    }

    // Wn tail output (864 floats), once (gid is a bijection of thread id).
    if (gid < (long long)(M_ROWS * A_ADC)) {
        __builtin_nontemporal_store(W[gid] + nz[gid] * 0.1f, &out_Wn[gid]);
    }

    // Software pipeline, depth 2: xv = x[i], xn1 = x[i+T].
    float xv  = (gid < N)     ? x[gid]     : 0.0f;
    float xn1 = (gid + T < N) ? x[gid + T] : 0.0f;

    for (long long i = gid; i < N; i += T) {
        // Prefetch x[i+2T] FIRST — before this iteration's stores enter the
        // VMEM FIFO — so the load consumed two iterations from now is older
        // than every store that could gate its s_waitcnt.
        const long long i2 = i + 2 * T;
        float xn2 = 0.0f;
        if (i2 < N) xn2 = x[i2];

        float q[B_BITS];

        // Bit-serial SAR, fully unrolled; m indices are compile-time.
        int m = M_ROWS - 1;
#pragma unroll
        for (int jj = 0; jj < B_BITS; ++jj) {
            const int j = B_BITS - 1 - jj;
            float bs = c[m]; --m;          // Wn[m]*VREF
#pragma unroll
            for (int k = j + 1; k < B_BITS; ++k) {
                // (q_k + 1)*0.5 in {0, 0.5, 1} -> product exact; add in
                // the same k-ascending order as the reference.
                float t = (q[k] + 1.0f) * 0.5f;
                bs += t * c[m];
                --m;
            }
            float s = (xv - bs) + 1e-30f;
            q[j] = (s > 0.0f) ? 1.0f : ((s < 0.0f) ? -1.0f : 0.0f);
        }

        // q = sum_j (q_j+1)/2 * (0.225 * 2^j), ascending j
        float acc = 0.0f;
#pragma unroll
        for (int j = 0; j < B_BITS; ++j) {
            float t = (q[j] + 1.0f) * 0.5f;
            float bwj = 0.225f * (float)(1 << j);  // exact pow2 scaling
            acc += t * bwj;
        }
        __builtin_nontemporal_store(acc, &out_q[i]);

        // --- Q output via LDS staging ---
        // Wave's 64 consecutive elements form a dense 2KB region of Q.
        // Stage 8 floats/lane, flush as two contiguous-1KB instructions.
        f32x4 v0; v0.x = q[0]; v0.y = q[1]; v0.z = q[2]; v0.w = q[3];
        f32x4 v1; v1.x = q[4]; v1.y = q[5]; v1.z = q[6]; v1.w = q[7];
        const int c0 = 2 * l, c1 = 2 * l + 1;
        stage[w][swz(c0)] = v0;
        stage[w][swz(c1)] = v1;
        // wave-private region: no barrier needed; compiler inserts lgkmcnt.
        const long long base_w = i - l;              // wave's first element
        f32x4* Qw = (f32x4*)(out_Q + base_w * 8);    // float4 index space
        const int r0 = l, r1 = 64 + l;
        __builtin_nontemporal_store(stage[w][swz(r0)], &Qw[r0]);
        __builtin_nontemporal_store(stage[w][swz(r1)], &Qw[r1]);

        xv = xn1;
        xn1 = xn2;
    }
}

extern "C" void kernel_launch(void* const* d_in, const int* in_sizes, int n_in,
                              void* d_out, int out_size, void* d_ws, size_t ws_size,
                              hipStream_t stream) {
    const float* x  = (const float*)d_in[0];
    const float* W  = (const float*)d_in[1];
    const float* nz = (const float*)d_in[2];
    float* out = (float*)d_out;

    const long long N = (long long)L_TOT * A_ADC;   // 12,582,912
    float* out_q  = out;
    float* out_Q  = out + N;
    float* out_Wn = out + N + N * (long long)B_BITS;

    // 2048 blocks x 384 threads: stride = 786432 (multiple of 24),
    // exactly 16 grid-stride iterations.
    sar_kernel<<<NBLK, BLK, 0, stream>>>(x, W, nz, out_q, out_Q, out_Wn, N);
}